// Round 12
// baseline (349.276 us; speedup 1.0000x reference)
//
#include <hip/hip_runtime.h>

#define N_NEUR 256
#define N_EDGE 1024
#define BATCH  128
#define HWDIM  28
#define IMG    784
#define FCH    200
#define NCLS   10
#define INF_W  0x3fffffff
#define SLOTS  257        // 256 neurons + X slot
#define XSLOT  256
#define TSZ    1024       // padded 32x32 tile
#define NT1    1024
#define NWAVE  16

// ws layout (floats): act[BATCH][SLOTS][TSZ] | hidden[BATCH][FCH] | gsched(int)[1+N_EDGE]
#define ACT_FLOATS ((size_t)BATCH * SLOTS * TSZ)

// ============================ kernel 1: all convs ============================
// One block per batch element (block-private slab, zero cross-block traffic).
// Wave = one full node (R9 mapping: best FMA per LDS byte). Explicit 2-phase
// pipeline with sched_barrier(0) pinning the prefetch loads ABOVE the compute
// (R10/R11 lesson: the scheduler otherwise sinks them to their use site).
__global__ __launch_bounds__(NT1, 4)
void conv_kernel(const float* __restrict__ x, const int* __restrict__ src,
                 const int* __restrict__ tgt, const float* __restrict__ conv_w,
                 const float* __restrict__ conv_b, float* __restrict__ act,
                 int* __restrict__ gsched, int cmax)
{
    const int tid = threadIdx.x;
    const int b   = blockIdx.x;

    __shared__ float s_tiles[NWAVE][2][TSZ];   // 128 KB; head aliased in phase 0
    __shared__ int   s_off[N_NEUR + 2];
    __shared__ int   s_dat[N_EDGE];
    __shared__ int   s_wn[N_NEUR];
    __shared__ int   s_wo[N_NEUR + 2];
    __shared__ int   s_na[N_NEUR];
    __shared__ int   s_W;
    __shared__ int   s_done;

    // ---------- phase 0: schedule build (every block, redundant; BFS temp aliased) ------
    int* e_src = (int*)&s_tiles[0][0][0];
    int* e_tgt = e_src + N_EDGE;
    int* wv    = e_tgt + N_EDGE;

    if (tid < N_EDGE) { e_src[tid] = src[tid]; e_tgt[tid] = tgt[tid]; }
    if (tid < N_NEUR) wv[tid] = (tid == 0) ? 0 : INF_W;
    __syncthreads();
    for (int w = 0; w < N_NEUR; ++w) {
        if (tid == 0) s_done = (wv[N_NEUR - 1] != INF_W);
        __syncthreads();
        if (s_done) break;
        {
            int s = e_src[tid], t = e_tgt[tid];   // 1024 threads = 1024 edges
            if (wv[s] == w && wv[t] == INF_W) wv[t] = w + 1;
        }
        __syncthreads();
    }
    if (tid < N_NEUR) {            // active in-channel counts (wave[u] < wave[v])
        int na = 0;
        const int wvv = wv[tid];
        for (int e = 0; e < N_EDGE; ++e)
            if (e_tgt[e] == tid && wv[e_src[e]] < wvv) ++na;
        if (tid == 0) na = 1;      // neuron 0: synthetic X input, channel 0
        s_na[tid] = na;
    }
    __syncthreads();
    if (tid == 0) {
        int o = 0;
        for (int v = 0; v < N_NEUR; ++v) { s_off[v] = o; o += s_na[v]; }
        s_off[N_NEUR] = o;
        s_W = wv[N_NEUR - 1];
    }
    __syncthreads();
    if (tid < N_NEUR) {            // CSR fill: packed u | (c<<9), c = edge-order channel idx
        if (tid == 0) {
            s_dat[s_off[0]] = XSLOT;
        } else {
            int o = s_off[tid], c = 0;
            const int wvv = wv[tid];
            for (int e = 0; e < N_EDGE; ++e) {
                if (e_tgt[e] == tid) {
                    if (wv[e_src[e]] < wvv) s_dat[o++] = e_src[e] | (c << 9);
                    ++c;
                }
            }
        }
    }
    __syncthreads();
    {   // wave-sorted conv node list (excludes FC node 255)
        const int Wl = s_W;
        if (tid <= Wl + 1) {
            int cn = 0;
            for (int v2 = 0; v2 < N_NEUR - 1; ++v2) if (wv[v2] < tid) ++cn;
            s_wo[tid] = cn;
        }
        if (tid < N_NEUR - 1 && wv[tid] <= Wl) {
            int pos = 0; const int mw = wv[tid];
            for (int v2 = 0; v2 < N_NEUR - 1; ++v2) {
                int w2 = wv[v2];
                if (w2 < mw || (w2 == mw && v2 < tid)) ++pos;
            }
            s_wn[pos] = tid;
        }
    }
    __syncthreads();
    {   // publish FC node's list for kernels 2/3 (all blocks write identical values)
        const int naL = s_off[N_NEUR] - s_off[N_NEUR - 1];
        if (tid == 0) gsched[0] = naL;
        if (tid < naL) gsched[1 + tid] = s_dat[s_off[N_NEUR - 1] + tid];
    }
    // zero halos of my 257 tiles (interior always written before read)
    for (int u = tid; u < SLOTS * 72; u += NT1) {
        const int t = u % 72, tile = u / 72;
        float* tp = act + (((size_t)b * SLOTS + tile) << 10);
        if (t < 16) {
            int eb = (t < 8) ? t * 8 : 960 + (t - 8) * 8;
            float4 z = make_float4(0.f, 0.f, 0.f, 0.f);
            ((float4*)(tp + eb))[0] = z; ((float4*)(tp + eb))[1] = z;
        } else {
            int s = t - 16;
            int eb = (2 + (s >> 1)) * 32 + ((s & 1) ? 30 : 0);
            *((float2*)(tp + eb)) = make_float2(0.f, 0.f);
        }
    }
    // stage my batch's x into the X slot
    for (int u = tid; u < 196; u += NT1) {
        const int row = u / 7, col = (u - row * 7) * 4;
        float4 v4 = *(const float4*)(x + b * IMG + row * HWDIM + col);
        float* tp = act + (((size_t)b * SLOTS + XSLOT) << 10) + (row + 2) * 32 + col + 2;
        *(float2*)tp       = make_float2(v4.x, v4.y);
        *(float2*)(tp + 2) = make_float2(v4.z, v4.w);
    }
    __syncthreads();   // s_tiles alias region free from here

    // ---------------- conv main loop: wave = one node, 4x4 px per lane ----------------
    const int wid  = tid >> 6;
    const int lane = tid & 63;
    const bool la  = lane < 49;
    const int cy   = lane / 7, cx = lane - 7 * (lane / 7);
    float* bufA = &s_tiles[wid][0][0];
    float* bufB = &s_tiles[wid][1][0];

    auto loadStg = [&](float4* st, int oo) {
        const int uu = __builtin_amdgcn_readfirstlane(s_dat[oo]) & 511;
        const float4* gs = (const float4*)(act + (((size_t)b * SLOTS + uu) << 10));
        #pragma unroll
        for (int i = 0; i < 4; ++i) st[i] = gs[lane + 64 * i];
    };
    auto loadWg = [&](float* wg, int oo) {
        const int pk = __builtin_amdgcn_readfirstlane(s_dat[oo]);
        const int v2 = __builtin_amdgcn_readfirstlane(s_wn[0]);   // dummy init avoided below
        (void)v2;
        return pk;   // caller combines with node id (kept for clarity)
    };
    (void)loadWg;
    auto storeLds = [&](float* buf, const float4* st) {
        float4* b4 = (float4*)buf;
        #pragma unroll
        for (int i = 0; i < 4; ++i) {
            const int fl = lane + 64 * i;
            const int lr = fl >> 3, cg = fl & 7;
            b4[(lr << 3) | (cg ^ ((lr >> 2) & 7))] = st[i];
        }
    };

    for (int w = 0; w <= s_W; ++w) {
        for (int ni = s_wo[w] + wid; ni < s_wo[w + 1]; ni += NWAVE) {
            const int v  = __builtin_amdgcn_readfirstlane(s_wn[ni]);
            const int o0 = s_off[v], o1 = s_off[v + 1];
            const float bias = conv_b[v];
            float acc[16];
            #pragma unroll
            for (int k = 0; k < 16; ++k) acc[k] = bias;

            float4 sA[4], sB[4];
            float  wA[25], wB[25];
            loadStg(sA, o0);
            {
                const int pk = __builtin_amdgcn_readfirstlane(s_dat[o0]);
                const float* wp = conv_w + ((size_t)v * cmax + (pk >> 9)) * 25;
                #pragma unroll
                for (int k = 0; k < 25; ++k) wA[k] = wp[k];
            }
            if (o0 + 1 < o1) {
                loadStg(sB, o0 + 1);
                const int pk = __builtin_amdgcn_readfirstlane(s_dat[o0 + 1]);
                const float* wp = conv_w + ((size_t)v * cmax + (pk >> 9)) * 25;
                #pragma unroll
                for (int k = 0; k < 25; ++k) wB[k] = wp[k];
            }

            auto computeBuf = [&](const float* buf, const float* wg) {
                if (!la) return;
                const float4* b4 = (const float4*)buf;
                #pragma unroll
                for (int r = 0; r < 8; ++r) {
                    const int row = 4 * cy + r;
                    const int sw  = (row >> 2) & 7;
                    float4 fa = b4[(row << 3) | (cx ^ sw)];
                    float4 fb = b4[(row << 3) | ((cx + 1) ^ sw)];
                    const float f[8] = {fa.x, fa.y, fa.z, fa.w, fb.x, fb.y, fb.z, fb.w};
                    #pragma unroll
                    for (int i = 0; i < 4; ++i) {
                        const int tr = r - i;
                        if (tr < 0 || tr > 4) continue;
                        #pragma unroll
                        for (int dx = 0; dx < 5; ++dx) {
                            const float wvv = wg[tr * 5 + dx];
                            #pragma unroll
                            for (int j = 0; j < 4; ++j)
                                acc[i * 4 + j] = fmaf(f[j + dx], wvv, acc[i * 4 + j]);
                        }
                    }
                }
            };

            int o = o0;
            while (true) {
                // ---- phase A: channel o (tile sA -> bufA, weights wA) ----
                storeLds(bufA, sA);                       // vmcnt waits on sA here
                if (o + 2 < o1) loadStg(sA, o + 2);       // issue tile prefetch (o+2)
                __builtin_amdgcn_sched_barrier(0);        // PIN: loads stay above compute
                computeBuf(bufA, wA);
                if (o + 2 < o1) {                         // scalar weight prefetch (o+2)
                    const int pk = __builtin_amdgcn_readfirstlane(s_dat[o + 2]);
                    const float* wp = conv_w + ((size_t)v * cmax + (pk >> 9)) * 25;
                    #pragma unroll
                    for (int k = 0; k < 25; ++k) wA[k] = wp[k];
                }
                ++o; if (o >= o1) break;
                // ---- phase B: channel o (tile sB -> bufB, weights wB) ----
                storeLds(bufB, sB);
                if (o + 2 < o1) loadStg(sB, o + 2);
                __builtin_amdgcn_sched_barrier(0);
                computeBuf(bufB, wB);
                if (o + 2 < o1) {
                    const int pk = __builtin_amdgcn_readfirstlane(s_dat[o + 2]);
                    const float* wp = conv_w + ((size_t)v * cmax + (pk >> 9)) * 25;
                    #pragma unroll
                    for (int k = 0; k < 25; ++k) wB[k] = wp[k];
                }
                ++o; if (o >= o1) break;
            }

            if (la) {   // relu + store 4x4 cell
                float* gd = act + (((size_t)b * SLOTS + v) << 10);
                #pragma unroll
                for (int i = 0; i < 4; ++i) {
                    float* p = gd + (2 + 4 * cy + i) * 32 + 2 + 4 * cx;
                    *(float2*)p       = make_float2(fmaxf(acc[i*4+0], 0.f), fmaxf(acc[i*4+1], 0.f));
                    *(float2*)(p + 2) = make_float2(fmaxf(acc[i*4+2], 0.f), fmaxf(acc[i*4+3], 0.f));
                }
            }
        }
        __syncthreads();   // DAG-wave boundary (intra-block only)
    }
}

// ============================ kernel 2: FC1 (tiled GEMM) ============================
#define FC1_BT 16
#define FC1_HT 16
#define FC1_STRIDE 900     // floats per batch row in LDS (bank-spread, 16B-aligned)

__global__ __launch_bounds__(256, 2)
void fc1_kernel(const float* __restrict__ act, const float* __restrict__ fc1_w,
                const float* __restrict__ fc1_b, float* __restrict__ hidden,
                const int* __restrict__ gsched, int dlast)
{
    const int tid = threadIdx.x;
    const int bt  = blockIdx.x & 7;        // 8 b-tiles
    const int ht  = blockIdx.x >> 3;       // 13 h-tiles
    const int b0  = bt * FC1_BT;
    const int h0  = ht * FC1_HT;
    __shared__ float s_act[FC1_BT * FC1_STRIDE];   // 57.6KB
    const int naL = gsched[0];
    const int bb  = tid & 15, hh = tid >> 4;
    const int h   = h0 + hh;
    float acc = 0.f;

    for (int a = 0; a < naL; ++a) {
        const int pk = gsched[1 + a];
        const int u = pk & 511, k = pk >> 9;
        __syncthreads();   // LDS reuse guard
        for (int idx = tid; idx < FC1_BT * 224; idx += 256) {   // 28 rows x 8 f4 x 16 b
            const int bi = idx / 224, rr = idx - bi * 224;
            const int r = rr >> 3, cg = rr & 7;
            const float4 vv = *((const float4*)(act +
                (((size_t)(b0 + bi) * SLOTS + u) << 10) + (r + 2) * 32) + cg);
            *(float4*)(&s_act[bi * FC1_STRIDE + r * 32 + cg * 4]) = vv;
        }
        __syncthreads();
        if (h < FCH) {
            const float* wrow = fc1_w + (size_t)h * ((size_t)dlast * IMG) + (size_t)k * IMG;
            const float* Tb   = &s_act[bb * FC1_STRIDE];
            for (int r = 0; r < HWDIM; ++r) {
                const float4* w4 = (const float4*)(wrow + r * HWDIM);
                const float*  tr = Tb + r * 32 + 2;
                #pragma unroll
                for (int q = 0; q < 7; ++q) {
                    const float4 wv = w4[q];
                    acc = fmaf(tr[4*q+0], wv.x, acc);
                    acc = fmaf(tr[4*q+1], wv.y, acc);
                    acc = fmaf(tr[4*q+2], wv.z, acc);
                    acc = fmaf(tr[4*q+3], wv.w, acc);
                }
            }
        }
    }
    if (h < FCH) hidden[(b0 + bb) * FCH + h] = fmaxf(acc + fc1_b[h], 0.f);
}

// ============================ kernel 3: FC2 + log_softmax ============================
__global__ __launch_bounds__(128, 1)
void fc2_kernel(const float* __restrict__ hidden, const float* __restrict__ fc2_w,
                const float* __restrict__ fc2_b, float* __restrict__ dout)
{
    const int b = threadIdx.x;   // 128 threads, 1 block
    float hr[FCH];
    const float* hp = hidden + b * FCH;
    for (int h = 0; h < FCH; h += 2) {
        float2 v2 = *(const float2*)(hp + h);
        hr[h] = v2.x; hr[h + 1] = v2.y;
    }
    float lg[NCLS], m = -1e30f;
    #pragma unroll
    for (int c = 0; c < NCLS; ++c) {
        float a2 = fc2_b[c];
        const float* wr = fc2_w + c * FCH;
        for (int hh = 0; hh < FCH; ++hh) a2 = fmaf(hr[hh], wr[hh], a2);
        lg[c] = a2;
        m = fmaxf(m, a2);
    }
    float s = 0.0f;
    #pragma unroll
    for (int c = 0; c < NCLS; ++c) s += expf(lg[c] - m);
    const float ls = m + logf(s);
    #pragma unroll
    for (int c = 0; c < NCLS; ++c) dout[b * NCLS + c] = lg[c] - ls;
}

extern "C" void kernel_launch(void* const* d_in, const int* in_sizes, int n_in,
                              void* d_out, int out_size, void* d_ws, size_t ws_size,
                              hipStream_t stream) {
    const float* x      = (const float*)d_in[0];
    const int*   src    = (const int*)d_in[1];
    const int*   tgt    = (const int*)d_in[2];
    const float* conv_w = (const float*)d_in[3];
    const float* conv_b = (const float*)d_in[4];
    const float* fc1_w  = (const float*)d_in[5];
    const float* fc1_b  = (const float*)d_in[6];
    const float* fc2_w  = (const float*)d_in[7];
    const float* fc2_b  = (const float*)d_in[8];
    float* out = (float*)d_out;
    float* ws  = (float*)d_ws;

    const int cmax  = in_sizes[3] / (N_NEUR * 25);   // conv_w: [256,1,cmax,5,5]
    const int dlast = in_sizes[5] / (FCH * IMG);     // fc1_w:  [200, dlast*784]

    float* act    = ws;
    float* hidden = ws + ACT_FLOATS;
    int*   gsched = (int*)(hidden + BATCH * FCH);

    hipLaunchKernelGGL(conv_kernel, dim3(BATCH), dim3(NT1), 0, stream,
                       x, src, tgt, conv_w, conv_b, act, gsched, cmax);
    hipLaunchKernelGGL(fc1_kernel, dim3(104), dim3(256), 0, stream,
                       act, fc1_w, fc1_b, hidden, gsched, dlast);
    hipLaunchKernelGGL(fc2_kernel, dim3(1), dim3(128), 0, stream,
                       hidden, fc2_w, fc2_b, out);
}

// Round 13
// 311.305 us; speedup vs baseline: 1.1220x; 1.1220x over previous
//
#include <hip/hip_runtime.h>

#define N_NEUR 256
#define N_EDGE 1024
#define BATCH  128
#define HWDIM  28
#define IMG    784
#define FCH    200
#define NCLS   10
#define INF_W  0x3fffffff
#define SLOTS  257        // 256 neurons + X slot
#define XSLOT  256
#define TSZ    1024       // padded 32x32 tile
#define NT1    1024
#define NWAVE  16

// ws layout (floats): act[BATCH][SLOTS][TSZ] | hidden[BATCH][FCH] | gsched(int)[1+N_EDGE]
#define ACT_FLOATS ((size_t)BATCH * SLOTS * TSZ)

// ============================ kernel 1: all convs ============================
// One block per batch element (block-private slab, zero cross-block traffic).
// Wave = one node; lane = 4x4 output patch. L1-DIRECT reads: each lane loads its
// 8x8 input patch (16 aligned float4) straight from the padded global tile.
// Row r's registers die at compute-row r -> compiler emits a natural vmcnt
// pipeline (16 outstanding loads). No ds_write/lgkm chain (the R9-R12 stall).
__global__ __launch_bounds__(NT1, 4)
void conv_kernel(const float* __restrict__ x, const int* __restrict__ src,
                 const int* __restrict__ tgt, const float* __restrict__ conv_w,
                 const float* __restrict__ conv_b, float* __restrict__ act,
                 int* __restrict__ gsched, int cmax)
{
    const int tid = threadIdx.x;
    const int b   = blockIdx.x;

    __shared__ int e_src[N_EDGE];
    __shared__ int e_tgt[N_EDGE];
    __shared__ int wvs[N_NEUR];
    __shared__ int s_off[N_NEUR + 2];
    __shared__ int s_dat[N_EDGE];
    __shared__ int s_wn[N_NEUR];
    __shared__ int s_wo[N_NEUR + 2];
    __shared__ int s_na[N_NEUR];
    __shared__ int s_W;
    __shared__ int s_done;

    // ---------- phase 0: schedule build (every block, redundant) ------
    if (tid < N_EDGE) { e_src[tid] = src[tid]; e_tgt[tid] = tgt[tid]; }
    if (tid < N_NEUR) wvs[tid] = (tid == 0) ? 0 : INF_W;
    __syncthreads();
    for (int w = 0; w < N_NEUR; ++w) {
        if (tid == 0) s_done = (wvs[N_NEUR - 1] != INF_W);
        __syncthreads();
        if (s_done) break;
        {
            int s = e_src[tid], t = e_tgt[tid];   // 1024 threads = 1024 edges
            if (wvs[s] == w && wvs[t] == INF_W) wvs[t] = w + 1;
        }
        __syncthreads();
    }
    if (tid < N_NEUR) {            // active in-channel counts (wave[u] < wave[v])
        int na = 0;
        const int wvv = wvs[tid];
        for (int e = 0; e < N_EDGE; ++e)
            if (e_tgt[e] == tid && wvs[e_src[e]] < wvv) ++na;
        if (tid == 0) na = 1;      // neuron 0: synthetic X input, channel 0
        s_na[tid] = na;
    }
    __syncthreads();
    if (tid == 0) {
        int o = 0;
        for (int v = 0; v < N_NEUR; ++v) { s_off[v] = o; o += s_na[v]; }
        s_off[N_NEUR] = o;
        s_W = wvs[N_NEUR - 1];
    }
    __syncthreads();
    if (tid < N_NEUR) {            // CSR fill: packed u | (c<<9), c = edge-order channel idx
        if (tid == 0) {
            s_dat[s_off[0]] = XSLOT;
        } else {
            int o = s_off[tid], c = 0;
            const int wvv = wvs[tid];
            for (int e = 0; e < N_EDGE; ++e) {
                if (e_tgt[e] == tid) {
                    if (wvs[e_src[e]] < wvv) s_dat[o++] = e_src[e] | (c << 9);
                    ++c;
                }
            }
        }
    }
    __syncthreads();
    {   // wave-sorted conv node list (excludes FC node 255)
        const int Wl = s_W;
        if (tid <= Wl + 1) {
            int cn = 0;
            for (int v2 = 0; v2 < N_NEUR - 1; ++v2) if (wvs[v2] < tid) ++cn;
            s_wo[tid] = cn;
        }
        if (tid < N_NEUR - 1 && wvs[tid] <= Wl) {
            int pos = 0; const int mw = wvs[tid];
            for (int v2 = 0; v2 < N_NEUR - 1; ++v2) {
                int w2 = wvs[v2];
                if (w2 < mw || (w2 == mw && v2 < tid)) ++pos;
            }
            s_wn[pos] = tid;
        }
    }
    __syncthreads();
    {   // publish FC node's list for kernels 2/3 (all blocks write identical values)
        const int naL = s_off[N_NEUR] - s_off[N_NEUR - 1];
        if (tid == 0) gsched[0] = naL;
        if (tid < naL) gsched[1 + tid] = s_dat[s_off[N_NEUR - 1] + tid];
    }
    // zero halos of my 257 tiles (interior always written before read)
    for (int u = tid; u < SLOTS * 72; u += NT1) {
        const int t = u % 72, tile = u / 72;
        float* tp = act + (((size_t)b * SLOTS + tile) << 10);
        if (t < 16) {
            int eb = (t < 8) ? t * 8 : 960 + (t - 8) * 8;
            float4 z = make_float4(0.f, 0.f, 0.f, 0.f);
            ((float4*)(tp + eb))[0] = z; ((float4*)(tp + eb))[1] = z;
        } else {
            int s = t - 16;
            int eb = (2 + (s >> 1)) * 32 + ((s & 1) ? 30 : 0);
            *((float2*)(tp + eb)) = make_float2(0.f, 0.f);
        }
    }
    // stage my batch's x into the X slot
    for (int u = tid; u < 196; u += NT1) {
        const int row = u / 7, col = (u - row * 7) * 4;
        float4 v4 = *(const float4*)(x + b * IMG + row * HWDIM + col);
        float* tp = act + (((size_t)b * SLOTS + XSLOT) << 10) + (row + 2) * 32 + col + 2;
        *(float2*)tp       = make_float2(v4.x, v4.y);
        *(float2*)(tp + 2) = make_float2(v4.z, v4.w);
    }
    __syncthreads();

    // ---------------- conv main loop: wave = one node, 4x4 px per lane ----------------
    const int wid  = tid >> 6;
    const int lane = tid & 63;
    const bool la  = lane < 49;
    const int cy   = lane / 7, cx = lane - 7 * (lane / 7);

    for (int w = 0; w <= s_W; ++w) {
        for (int ni = s_wo[w] + wid; ni < s_wo[w + 1]; ni += NWAVE) {
            const int v  = __builtin_amdgcn_readfirstlane(s_wn[ni]);
            const int o0 = s_off[v], o1 = s_off[v + 1];
            const float bias = conv_b[v];
            float acc[16];
            #pragma unroll
            for (int k = 0; k < 16; ++k) acc[k] = bias;

            for (int o = o0; o < o1; ++o) {
                const int pk = __builtin_amdgcn_readfirstlane(s_dat[o]);
                const int u  = pk & 511;
                const int c  = pk >> 9;
                const float4* gs = (const float4*)(act + (((size_t)b * SLOTS + u) << 10));
                const float*  wp = conv_w + ((size_t)v * cmax + c) * 25;
                float wg[25];
                #pragma unroll
                for (int k = 0; k < 25; ++k) wg[k] = wp[k];
                if (la) {
                    // 16 direct loads; row r consumed at iteration r -> vmcnt pipeline
                    float4 fa[8], fb[8];
                    #pragma unroll
                    for (int r = 0; r < 8; ++r) {
                        const int ro = (4 * cy + r) * 8 + cx;
                        fa[r] = gs[ro];
                        fb[r] = gs[ro + 1];
                    }
                    #pragma unroll
                    for (int r = 0; r < 8; ++r) {
                        const float f[8] = {fa[r].x, fa[r].y, fa[r].z, fa[r].w,
                                            fb[r].x, fb[r].y, fb[r].z, fb[r].w};
                        #pragma unroll
                        for (int i = 0; i < 4; ++i) {
                            const int tr = r - i;
                            if (tr < 0 || tr > 4) continue;
                            #pragma unroll
                            for (int dx = 0; dx < 5; ++dx) {
                                const float wvv = wg[tr * 5 + dx];
                                #pragma unroll
                                for (int j = 0; j < 4; ++j)
                                    acc[i * 4 + j] = fmaf(f[j + dx], wvv, acc[i * 4 + j]);
                            }
                        }
                    }
                }
            }

            if (la) {   // relu + store 4x4 cell
                float* gd = act + (((size_t)b * SLOTS + v) << 10);
                #pragma unroll
                for (int i = 0; i < 4; ++i) {
                    float* p = gd + (2 + 4 * cy + i) * 32 + 2 + 4 * cx;
                    *(float2*)p       = make_float2(fmaxf(acc[i*4+0], 0.f), fmaxf(acc[i*4+1], 0.f));
                    *(float2*)(p + 2) = make_float2(fmaxf(acc[i*4+2], 0.f), fmaxf(acc[i*4+3], 0.f));
                }
            }
        }
        __syncthreads();   // DAG-wave boundary (intra-block only)
    }
}

// ============================ kernel 2: FC1 (tiled GEMM) ============================
#define FC1_BT 16
#define FC1_HT 16
#define FC1_STRIDE 900     // floats per batch row in LDS (bank-spread, 16B-aligned)

__global__ __launch_bounds__(256, 2)
void fc1_kernel(const float* __restrict__ act, const float* __restrict__ fc1_w,
                const float* __restrict__ fc1_b, float* __restrict__ hidden,
                const int* __restrict__ gsched, int dlast)
{
    const int tid = threadIdx.x;
    const int bt  = blockIdx.x & 7;        // 8 b-tiles
    const int ht  = blockIdx.x >> 3;       // 13 h-tiles
    const int b0  = bt * FC1_BT;
    const int h0  = ht * FC1_HT;
    __shared__ float s_act[FC1_BT * FC1_STRIDE];   // 57.6KB
    const int naL = gsched[0];
    const int bb  = tid & 15, hh = tid >> 4;
    const int h   = h0 + hh;
    float acc = 0.f;

    for (int a = 0; a < naL; ++a) {
        const int pk = gsched[1 + a];
        const int u = pk & 511, k = pk >> 9;
        __syncthreads();   // LDS reuse guard
        for (int idx = tid; idx < FC1_BT * 224; idx += 256) {   // 28 rows x 8 f4 x 16 b
            const int bi = idx / 224, rr = idx - bi * 224;
            const int r = rr >> 3, cg = rr & 7;
            const float4 vv = *((const float4*)(act +
                (((size_t)(b0 + bi) * SLOTS + u) << 10) + (r + 2) * 32) + cg);
            *(float4*)(&s_act[bi * FC1_STRIDE + r * 32 + cg * 4]) = vv;
        }
        __syncthreads();
        if (h < FCH) {
            const float* wrow = fc1_w + (size_t)h * ((size_t)dlast * IMG) + (size_t)k * IMG;
            const float* Tb   = &s_act[bb * FC1_STRIDE];
            for (int r = 0; r < HWDIM; ++r) {
                const float4* w4 = (const float4*)(wrow + r * HWDIM);
                const float*  tr = Tb + r * 32 + 2;
                #pragma unroll
                for (int q = 0; q < 7; ++q) {
                    const float4 wv = w4[q];
                    acc = fmaf(tr[4*q+0], wv.x, acc);
                    acc = fmaf(tr[4*q+1], wv.y, acc);
                    acc = fmaf(tr[4*q+2], wv.z, acc);
                    acc = fmaf(tr[4*q+3], wv.w, acc);
                }
            }
        }
    }
    if (h < FCH) hidden[(b0 + bb) * FCH + h] = fmaxf(acc + fc1_b[h], 0.f);
}

// ============================ kernel 3: FC2 + log_softmax ============================
__global__ __launch_bounds__(128, 1)
void fc2_kernel(const float* __restrict__ hidden, const float* __restrict__ fc2_w,
                const float* __restrict__ fc2_b, float* __restrict__ dout)
{
    const int b = threadIdx.x;   // 128 threads, 1 block
    float hr[FCH];
    const float* hp = hidden + b * FCH;
    for (int h = 0; h < FCH; h += 2) {
        float2 v2 = *(const float2*)(hp + h);
        hr[h] = v2.x; hr[h + 1] = v2.y;
    }
    float lg[NCLS], m = -1e30f;
    #pragma unroll
    for (int c = 0; c < NCLS; ++c) {
        float a2 = fc2_b[c];
        const float* wr = fc2_w + c * FCH;
        for (int hh = 0; hh < FCH; ++hh) a2 = fmaf(hr[hh], wr[hh], a2);
        lg[c] = a2;
        m = fmaxf(m, a2);
    }
    float s = 0.0f;
    #pragma unroll
    for (int c = 0; c < NCLS; ++c) s += expf(lg[c] - m);
    const float ls = m + logf(s);
    #pragma unroll
    for (int c = 0; c < NCLS; ++c) dout[b * NCLS + c] = lg[c] - ls;
}

extern "C" void kernel_launch(void* const* d_in, const int* in_sizes, int n_in,
                              void* d_out, int out_size, void* d_ws, size_t ws_size,
                              hipStream_t stream) {
    const float* x      = (const float*)d_in[0];
    const int*   src    = (const int*)d_in[1];
    const int*   tgt    = (const int*)d_in[2];
    const float* conv_w = (const float*)d_in[3];
    const float* conv_b = (const float*)d_in[4];
    const float* fc1_w  = (const float*)d_in[5];
    const float* fc1_b  = (const float*)d_in[6];
    const float* fc2_w  = (const float*)d_in[7];
    const float* fc2_b  = (const float*)d_in[8];
    float* out = (float*)d_out;
    float* ws  = (float*)d_ws;

    const int cmax  = in_sizes[3] / (N_NEUR * 25);   // conv_w: [256,1,cmax,5,5]
    const int dlast = in_sizes[5] / (FCH * IMG);     // fc1_w:  [200, dlast*784]

    float* act    = ws;
    float* hidden = ws + ACT_FLOATS;
    int*   gsched = (int*)(hidden + BATCH * FCH);

    hipLaunchKernelGGL(conv_kernel, dim3(BATCH), dim3(NT1), 0, stream,
                       x, src, tgt, conv_w, conv_b, act, gsched, cmax);
    hipLaunchKernelGGL(fc1_kernel, dim3(104), dim3(256), 0, stream,
                       act, fc1_w, fc1_b, hidden, gsched, dlast);
    hipLaunchKernelGGL(fc2_kernel, dim3(1), dim3(128), 0, stream,
                       hidden, fc2_w, fc2_b, out);
}